// Round 9
// baseline (140.771 us; speedup 1.0000x reference)
//
#include <hip/hip_runtime.h>
#include <hip/hip_bf16.h>
#include <math.h>

#define VOCAB 2048
#define EMB 256
#define MAXLEN 8
#define NBATCH 16
#define LAT 16
#define NBLK2 128

typedef unsigned short u16;
using bf16x8 = __attribute__((ext_vector_type(8))) short;
using f32x4  = __attribute__((ext_vector_type(4))) float;

// token = argmax_j ( j/2048 <= v && v <= (j+1)/2048 ), 0 if none.
// cumsum of uniform softmax is exactly k/2048 in fp32; v*2048 is exact.
__device__ __forceinline__ int token_of(float v) {
    float u = v * 2048.0f;
    if (!(u >= 0.0f) || u > 2048.0f) return 0;   // v<0, v>1, or NaN
    int k = (int)ceilf(u) - 1;
    return k < 0 ? 0 : k;
}

__device__ __forceinline__ float sigmoidf_(float x) { return 1.0f / (1.0f + expf(-x)); }

__device__ __forceinline__ u16 to_bf16(float x) {
    __hip_bfloat16 hb = __float2bfloat16(x);   // RTNE
    return *reinterpret_cast<u16*>(&hb);
}

// Grid barrier: all NBLK2 blocks resident by construction (128 blocks <= 256 CUs).
// Release: threadfence before add. Acquire: threadfence after observing count.
__device__ __forceinline__ void gridbar(int* bar, int phase) {
    __syncthreads();
    if (threadIdx.x == 0) {
        __threadfence();
        atomicAdd(&bar[phase], 1);
        while (__hip_atomic_load(&bar[phase], __ATOMIC_RELAXED,
                                 __HIP_MEMORY_SCOPE_AGENT) < NBLK2) {
            __builtin_amdgcn_s_sleep(2);
        }
        __threadfence();
    }
    __syncthreads();
}

// ---- K1: merged pack kernel.
// blocks [0,8192): Wr -> BW (sh=6); [8192,9216): Wk -> BWk (sh=3);
// [9216,9232): XA = E[token] A-frags; block 9232: zero barrier counters.
// frag layout: dst[((ntile*nk0 + k0)*64 + l)*8 + i] =
//   bf16( W[(k0*32 + 8*(l>>4) + i)*8192 + ntile*16 + (l&15)] )
// (k-permutation within a fragment cancels: A uses the same map)
__global__ __launch_bounds__(256) void k_pack(
        const float* __restrict__ Wr, const float* __restrict__ Wk,
        const float* __restrict__ ip, const float* __restrict__ E,
        u16* __restrict__ BW, u16* __restrict__ BWk,
        u16* __restrict__ XA, int* __restrict__ bar) {
    int bx = blockIdx.x;
    int tid = threadIdx.x;
    if (bx < 8192) {
        int gidx = bx * 256 + tid;
        int l = gidx & 63;
        int k0 = (gidx >> 6) & 63;
        int ntile = gidx >> 12;
        const float* s = Wr + (size_t)(k0 * 32 + 8 * (l >> 4)) * 8192 + ntile * 16 + (l & 15);
        u16 o[8];
        #pragma unroll
        for (int i = 0; i < 8; ++i) o[i] = to_bf16(s[(size_t)i * 8192]);
        *(uint4*)(BW + (size_t)gidx * 8) = *(uint4*)o;
    } else if (bx < 9216) {
        int gidx = (bx - 8192) * 256 + tid;
        int l = gidx & 63;
        int k0 = (gidx >> 6) & 7;
        int ntile = gidx >> 9;
        const float* s = Wk + (size_t)(k0 * 32 + 8 * (l >> 4)) * 8192 + ntile * 16 + (l & 15);
        u16 o[8];
        #pragma unroll
        for (int i = 0; i < 8; ++i) o[i] = to_bf16(s[(size_t)i * 8192]);
        *(uint4*)(BWk + (size_t)gidx * 8) = *(uint4*)o;
    } else if (bx < 9232) {
        int gidx = (bx - 9216) * 256 + tid;   // 0..4095
        int l = gidx & 63;
        int k0 = (gidx >> 6) & 7;
        int t = gidx >> 9;
        int b = l & 15;
        int tok = token_of(ip[b * LAT + t]);
        const float* s = E + (size_t)tok * EMB + k0 * 32 + 8 * (l >> 4);
        u16 o[8];
        #pragma unroll
        for (int i = 0; i < 8; ++i) o[i] = to_bf16(s[i]);
        *(uint4*)(XA + (size_t)gidx * 8) = *(uint4*)o;
    } else {
        if (tid < 16) bar[tid] = 0;
    }
}

// ---- K2: persistent sequence kernel. 128 blocks x 1024 thr (16 waves).
// Phases: xz(all t) | bar0 | step0 | bar1 | 7x(step GEMM+update | bar) | softmax.
// Block bid owns u-tile [bid*16, bid*16+16); h,c live in registers of tid<256.
__global__ __launch_bounds__(1024, 4) void k_seq(
        const u16* __restrict__ BW, const u16* __restrict__ BWk,
        const u16* __restrict__ XA, const float* __restrict__ bv,
        const float* __restrict__ ip, float* __restrict__ xz,
        u16* __restrict__ hA0, u16* __restrict__ hA1,
        float* __restrict__ H, float* __restrict__ out, int* __restrict__ bar) {
    int tid = threadIdx.x;
    int bid = blockIdx.x;        // 0..127
    int w = tid >> 6;            // 0..15
    int l = tid & 63;

    __shared__ float zsh[16][256];
    __shared__ float redm[16], reds[16];

    // ---- Phase XZ: xz[t][g][b][u] = bias + X[t] @ Wk, all 8 timesteps ----
    {
        int wgid = bid * 16 + w;             // 0..2047
        int ntile = wgid >> 2;               // 0..511
        int tp = wgid & 3;                   // t-pair: t in {2tp, 2tp+1}
        const bf16x8* bp = (const bf16x8*)(BWk + ((size_t)(ntile * 8) * 64 + l) * 8);
        bf16x8 bw[8];
        #pragma unroll
        for (int s = 0; s < 8; ++s) bw[s] = bp[s * 64];
        float bias = bv[ntile * 16 + (l & 15)];
        int g = ntile >> 7;
        int u = (ntile & 127) * 16 + (l & 15);
        #pragma unroll
        for (int q = 0; q < 2; ++q) {
            int t = tp * 2 + q;
            const bf16x8* ap = (const bf16x8*)(XA + ((size_t)(t * 8) * 64 + l) * 8);
            f32x4 acc = {bias, bias, bias, bias};
            #pragma unroll
            for (int s = 0; s < 8; ++s)
                acc = __builtin_amdgcn_mfma_f32_16x16x32_bf16(ap[s * 64], bw[s], acc, 0, 0, 0);
            #pragma unroll
            for (int i = 0; i < 4; ++i) {
                int b = 4 * (l >> 4) + i;    // D row = batch (m89-verified C/D layout)
                xz[((size_t)((t * 4 + g) * NBATCH) + b) * 2048 + u] = acc[i];
            }
        }
    }
    gridbar(bar, 0);

    // ---- Phase step0: h=c=0 -> z = xz(t=0); registers c,h persist in tid<256 ----
    float c_reg = 0.0f, h_reg = 0.0f;
    int bb = tid >> 4;                       // batch (tid<256)
    int myu = bid * 16 + (tid & 15);         // owned u
    if (tid < 256) {
        float z0 = xz[((size_t)(0 * NBATCH) + bb) * 2048 + myu];
        float z2 = xz[((size_t)(2 * NBATCH) + bb) * 2048 + myu];
        float z3 = xz[((size_t)(3 * NBATCH) + bb) * 2048 + myu];
        float cn = sigmoidf_(z0) * tanhf(z2);
        float hn = sigmoidf_(z3) * tanhf(cn);
        int tok = token_of(ip[bb * LAT + 0]);
        h_reg = tok != 0 ? hn : 0.0f;
        c_reg = tok != 0 ? cn : 0.0f;
        H[bb * 2048 + myu] = h_reg;
        int k0 = myu >> 5, lg = (myu >> 3) & 3, i = myu & 7;
        hA1[((size_t)(k0 * 64) + lg * 16 + bb) * 8 + i] = to_bf16(h_reg);
    }
    gridbar(bar, 1);

    // ---- Steps 1..7: h @ Wr via MFMA + gates + masked update ----
    int g = w >> 2, kq = w & 3;              // wave = (gate, K-quarter)
    int ntile = g * 128 + bid;
    const bf16x8* bp = (const bf16x8*)(BW + (((size_t)ntile * 64 + kq * 16) * 64 + l) * 8);
    for (int t = 1; t < 8; ++t) {
        const u16* hAin = (t & 1) ? hA1 : hA0;
        u16* hAout = (t & 1) ? hA0 : hA1;
        const bf16x8* ap = (const bf16x8*)(hAin + ((size_t)(kq * 16) * 64 + l) * 8);
        f32x4 acc = {0.f, 0.f, 0.f, 0.f};
        bf16x8 br[8], ar[4];
        #pragma unroll
        for (int i = 0; i < 8; ++i) br[i] = bp[i * 64];
        #pragma unroll
        for (int i = 0; i < 4; ++i) ar[i] = ap[i * 64];
        #pragma unroll
        for (int s = 0; s < 16; ++s) {
            bf16x8 a = ar[s & 3];
            bf16x8 b = br[s & 7];
            if (s + 4 < 16) ar[s & 3] = ap[(s + 4) * 64];
            if (s + 8 < 16) br[s & 7] = bp[(s + 8) * 64];
            acc = __builtin_amdgcn_mfma_f32_16x16x32_bf16(a, b, acc, 0, 0, 0);
        }
        #pragma unroll
        for (int i = 0; i < 4; ++i)
            zsh[w][(4 * (l >> 4) + i) * 16 + (l & 15)] = acc[i];
        __syncthreads();
        if (tid < 256) {
            float z[4];
            #pragma unroll
            for (int gg = 0; gg < 4; ++gg) {
                float s = zsh[gg * 4 + 0][tid] + zsh[gg * 4 + 1][tid]
                        + zsh[gg * 4 + 2][tid] + zsh[gg * 4 + 3][tid];
                z[gg] = s + xz[((size_t)((t * 4 + gg) * NBATCH) + bb) * 2048 + myu];
            }
            float cn = sigmoidf_(z[1]) * c_reg + sigmoidf_(z[0]) * tanhf(z[2]);
            float hn = sigmoidf_(z[3]) * tanhf(cn);
            int tok = token_of(ip[bb * LAT + t]);
            h_reg = tok != 0 ? hn : h_reg;
            c_reg = tok != 0 ? cn : c_reg;
            H[(size_t)t * (NBATCH * VOCAB) + bb * 2048 + myu] = h_reg;
            int k0 = myu >> 5, lg = (myu >> 3) & 3, i = myu & 7;
            hAout[((size_t)(k0 * 64) + lg * 16 + bb) * 8 + i] = to_bf16(h_reg);
        }
        gridbar(bar, 1 + t);     // also orders zsh reuse across iterations
    }

    // ---- Softmax: block bid handles row r = bid (= t*16 + b) ----
    {
        int r = bid;
        int t = r >> 4, b = r & 15;
        const float* hr = H + (size_t)r * VOCAB;
        float v0 = hr[tid], v1 = hr[tid + 1024];
        float m = fmaxf(v0, v1);
        #pragma unroll
        for (int off = 32; off; off >>= 1) m = fmaxf(m, __shfl_down(m, off));
        if (l == 0) redm[w] = m;
        __syncthreads();
        m = redm[0];
        #pragma unroll
        for (int i = 1; i < 16; ++i) m = fmaxf(m, redm[i]);
        float e0 = expf(v0 - m), e1 = expf(v1 - m);
        float s = e0 + e1;
        #pragma unroll
        for (int off = 32; off; off >>= 1) s += __shfl_down(s, off);
        if (l == 0) reds[w] = s;
        __syncthreads();
        s = reds[0];
        #pragma unroll
        for (int i = 1; i < 16; ++i) s += reds[i];
        float* o = out + ((size_t)b * MAXLEN + t) * VOCAB;
        o[tid] = e0 / s;
        o[tid + 1024] = e1 / s;
    }
}

extern "C" void kernel_launch(void* const* d_in, const int* in_sizes, int n_in,
                              void* d_out, int out_size, void* d_ws, size_t ws_size,
                              hipStream_t stream) {
    const float* ip = (const float*)d_in[0];   // (16,16)
    const float* E  = (const float*)d_in[1];   // (2048,256)
    const float* Wk = (const float*)d_in[2];   // (256,8192)
    const float* Wr = (const float*)d_in[3];   // (2048,8192)
    const float* bv = (const float*)d_in[4];   // (8192,)

    char* w = (char*)d_ws;
    float* xz  = (float*)w;  w += (size_t)8 * 4 * NBATCH * 2048 * 4;   // 4 MB
    float* H   = (float*)w;  w += (size_t)262144 * 4;                  // 1 MB
    u16* XA  = (u16*)w;      w += (size_t)32768 * 2;                   // 64 KB
    u16* hA0 = (u16*)w;      w += (size_t)32768 * 2;
    u16* hA1 = (u16*)w;      w += (size_t)32768 * 2;
    u16* BWk = (u16*)w;      w += (size_t)2097152 * 2;                 // 4 MB
    u16* BW  = (u16*)w;      w += (size_t)16777216 * 2;                // 32 MB
    int* bar = (int*)w;      w += 64 * 4;

    k_pack<<<9233, 256, 0, stream>>>(Wr, Wk, ip, E, BW, BWk, XA, bar);
    k_seq<<<NBLK2, 1024, 0, stream>>>(BW, BWk, XA, bv, ip, xz, hA0, hA1,
                                      H, (float*)d_out, bar);
}

// Round 10
// 88.339 us; speedup vs baseline: 1.5935x; 1.5935x over previous
//
#include <hip/hip_runtime.h>
#include <hip/hip_bf16.h>
#include <math.h>

#define VOCAB 2048
#define EMB 256
#define MAXLEN 8
#define NBATCH 16
#define LAT 16

typedef unsigned short u16;
using bf16x8 = __attribute__((ext_vector_type(8))) short;
using f32x4  = __attribute__((ext_vector_type(4))) float;

// token = argmax_j ( j/2048 <= v && v <= (j+1)/2048 ), 0 if none.
// cumsum of uniform softmax is exactly k/2048 in fp32; v*2048 is exact.
__device__ __forceinline__ int token_of(float v) {
    float u = v * 2048.0f;
    if (!(u >= 0.0f) || u > 2048.0f) return 0;   // v<0, v>1, or NaN
    int k = (int)ceilf(u) - 1;
    return k < 0 ? 0 : k;
}

__device__ __forceinline__ float sigmoidf_(float x) { return 1.0f / (1.0f + expf(-x)); }

__device__ __forceinline__ u16 to_bf16(float x) {
    __hip_bfloat16 hb = __float2bfloat16(x);   // RTNE
    return *reinterpret_cast<u16*>(&hb);
}

// ---- K1: merged pack kernel.
// Fragment convention (both operands use the same k-map, so any in-fragment
// k-permutation cancels): frag(ntile, k0) element (l, i) =
//   bf16( W[(k0*32 + 8*(l>>4) + i)*8192 + ntile*16 + (l&15)] )
// STORAGE is block-contiguous: st = (ntile&127)*4 + (ntile>>7), so block bid's
// four gate-tiles {bid, 128+bid, 256+bid, 384+bid} occupy one 256 KB range.
// blocks [0,8192): Wr->BW; [8192,9216): Wk->BWk; [9216,9232): XA pack.
__global__ __launch_bounds__(256) void k_pack(
        const float* __restrict__ Wr, const float* __restrict__ Wk,
        const float* __restrict__ ip, const float* __restrict__ E,
        u16* __restrict__ BW, u16* __restrict__ BWk, u16* __restrict__ XA) {
    int bx = blockIdx.x;
    int tid = threadIdx.x;
    if (bx < 8192) {
        int gidx = bx * 256 + tid;
        int l = gidx & 63;
        int k0 = (gidx >> 6) & 63;
        int ntile = gidx >> 12;
        const float* s = Wr + (size_t)(k0 * 32 + 8 * (l >> 4)) * 8192 + ntile * 16 + (l & 15);
        u16 o[8];
        #pragma unroll
        for (int i = 0; i < 8; ++i) o[i] = to_bf16(s[(size_t)i * 8192]);
        int st = (ntile & 127) * 4 + (ntile >> 7);
        *(uint4*)(BW + ((size_t)(st * 64 + k0) * 64 + l) * 8) = *(uint4*)o;
    } else if (bx < 9216) {
        int gidx = (bx - 8192) * 256 + tid;
        int l = gidx & 63;
        int k0 = (gidx >> 6) & 7;
        int ntile = gidx >> 9;
        const float* s = Wk + (size_t)(k0 * 32 + 8 * (l >> 4)) * 8192 + ntile * 16 + (l & 15);
        u16 o[8];
        #pragma unroll
        for (int i = 0; i < 8; ++i) o[i] = to_bf16(s[(size_t)i * 8192]);
        int st = (ntile & 127) * 4 + (ntile >> 7);
        *(uint4*)(BWk + ((size_t)(st * 8 + k0) * 64 + l) * 8) = *(uint4*)o;
    } else {
        int gidx = (bx - 9216) * 256 + tid;   // 0..4095
        int l = gidx & 63;
        int k0 = (gidx >> 6) & 7;
        int t = gidx >> 9;
        int b = l & 15;
        int tok = token_of(ip[b * LAT + t]);
        const float* s = E + (size_t)tok * EMB + k0 * 32 + 8 * (l >> 4);
        u16 o[8];
        #pragma unroll
        for (int i = 0; i < 8; ++i) o[i] = to_bf16(s[i]);
        *(uint4*)(XA + (size_t)gidx * 8) = *(uint4*)o;
    }
}

// ---- K2: xz GEMM for all 8 timesteps + fused step0.
// 128 blocks x 1024 thr. wave w: gate g = w>>2, t-pair tp = w&3 (t = 2tp, 2tp+1);
// block bid owns u-tile [bid*16, bid*16+16) for ALL gates (st = bid*4+g).
__global__ __launch_bounds__(1024) void k_xzmm0(
        const u16* __restrict__ BWk, const u16* __restrict__ XA,
        const float* __restrict__ bv, const float* __restrict__ ip,
        float* __restrict__ xz, float* __restrict__ h, float* __restrict__ c,
        u16* __restrict__ hA1, float* __restrict__ H) {
    int tid = threadIdx.x;
    int bid = blockIdx.x;
    int w = tid >> 6;
    int l = tid & 63;
    int g = w >> 2, tp = w & 3;
    int st = bid * 4 + g;
    int u = bid * 16 + (l & 15);

    __shared__ float zsh[4][256];

    const bf16x8* bp = (const bf16x8*)(BWk + ((size_t)(st * 8) * 64 + l) * 8);
    bf16x8 bw[8];
    #pragma unroll
    for (int s = 0; s < 8; ++s) bw[s] = bp[s * 64];
    float bias = bv[g * 2048 + u];

    #pragma unroll
    for (int q = 0; q < 2; ++q) {
        int t = tp * 2 + q;
        const bf16x8* ap = (const bf16x8*)(XA + ((size_t)(t * 8) * 64 + l) * 8);
        f32x4 acc = {bias, bias, bias, bias};
        #pragma unroll
        for (int s = 0; s < 8; ++s)
            acc = __builtin_amdgcn_mfma_f32_16x16x32_bf16(ap[s * 64], bw[s], acc, 0, 0, 0);
        #pragma unroll
        for (int i = 0; i < 4; ++i) {
            int b = 4 * (l >> 4) + i;    // D row = batch (m89-verified C/D layout)
            xz[((size_t)((t * 4 + g) * NBATCH) + b) * 2048 + u] = acc[i];
            if (t == 0) zsh[g][b * 16 + (l & 15)] = acc[i];
        }
    }
    __syncthreads();

    // fused step0 (h=c=0): z = zsh (bias included); masked update
    if (tid < 256) {
        int bb = tid >> 4;
        int myu = bid * 16 + (tid & 15);
        float z0 = zsh[0][tid], z2 = zsh[2][tid], z3 = zsh[3][tid];
        float cn = sigmoidf_(z0) * tanhf(z2);
        float hn = sigmoidf_(z3) * tanhf(cn);
        int tok = token_of(ip[bb * LAT + 0]);
        float hw = tok != 0 ? hn : 0.0f;
        float cw = tok != 0 ? cn : 0.0f;
        h[bb * 2048 + myu] = hw;
        c[bb * 2048 + myu] = cw;
        H[bb * 2048 + myu] = hw;
        int k0 = myu >> 5, lg = (myu >> 3) & 3, i = myu & 7;
        hA1[((size_t)(k0 * 64) + lg * 16 + bb) * 8 + i] = to_bf16(hw);
    }
}

// ---- K3: fused step t>=1: h @ Wr via MFMA + gates + masked update.
// 128 blocks x 1024 thr = 16 waves: wave = (gate g, K-quarter kq).
// All 16 B-fragments register-prefetched up front (max MLP), A 4-deep rotated.
__global__ __launch_bounds__(1024) void k_step(const u16* __restrict__ BW,
        const u16* __restrict__ hAin, u16* __restrict__ hAout,
        const float* __restrict__ xz, const float* __restrict__ ip,
        float* __restrict__ h, float* __restrict__ c,
        float* __restrict__ H, int t) {
    int tid = threadIdx.x;
    int w = tid >> 6;            // 0..15
    int g = w >> 2, kq = w & 3;
    int l = tid & 63;
    int bid = blockIdx.x;        // 0..127
    int st = bid * 4 + g;

    const bf16x8* ap = (const bf16x8*)(hAin + ((size_t)(kq * 16) * 64 + l) * 8);
    const bf16x8* bp = (const bf16x8*)(BW + (((size_t)(st * 64) + kq * 16) * 64 + l) * 8);
    f32x4 acc = {0.f, 0.f, 0.f, 0.f};

    bf16x8 br[16], ar[4];
    #pragma unroll
    for (int i = 0; i < 16; ++i) br[i] = bp[i * 64];
    #pragma unroll
    for (int i = 0; i < 4; ++i) ar[i] = ap[i * 64];

    #pragma unroll
    for (int s = 0; s < 16; ++s) {
        bf16x8 a = ar[s & 3];
        if (s + 4 < 16) ar[s & 3] = ap[(s + 4) * 64];
        acc = __builtin_amdgcn_mfma_f32_16x16x32_bf16(a, br[s], acc, 0, 0, 0);
    }

    __shared__ float zsh[16][256];
    #pragma unroll
    for (int i = 0; i < 4; ++i)
        zsh[w][(4 * (l >> 4) + i) * 16 + (l & 15)] = acc[i];
    __syncthreads();

    if (tid < 256) {
        int bb = tid >> 4, ul = tid & 15;
        int myu = bid * 16 + ul;
        float z[4];
        #pragma unroll
        for (int gg = 0; gg < 4; ++gg) {
            float s = zsh[gg * 4 + 0][tid] + zsh[gg * 4 + 1][tid]
                    + zsh[gg * 4 + 2][tid] + zsh[gg * 4 + 3][tid];
            z[gg] = s + xz[((size_t)((t * 4 + gg) * NBATCH) + bb) * 2048 + myu];
        }
        int idx = bb * 2048 + myu;
        float co = c[idx], ho = h[idx];
        float cn = sigmoidf_(z[1]) * co + sigmoidf_(z[0]) * tanhf(z[2]);
        float hn = sigmoidf_(z[3]) * tanhf(cn);
        int tok = token_of(ip[bb * LAT + t]);
        float hw = tok != 0 ? hn : ho;
        float cw = tok != 0 ? cn : co;
        h[idx] = hw; c[idx] = cw;
        H[(size_t)t * (NBATCH * VOCAB) + idx] = hw;
        int k0 = myu >> 5, lg = (myu >> 3) & 3, i = myu & 7;
        hAout[((size_t)(k0 * 64) + lg * 16 + bb) * 8 + i] = to_bf16(hw);
    }
}

// ---- K4: softmax of all 128 recorded h rows -> d_out[b][t][:] ----
__global__ __launch_bounds__(256) void k_softmax(const float* __restrict__ H,
                                                 float* __restrict__ out) {
    int r = blockIdx.x;          // r = t*16 + b
    int t = r >> 4, b = r & 15;
    int tid = threadIdx.x;
    const float* hr = H + (size_t)r * VOCAB;
    float v[8];
    float m = -1e30f;
    #pragma unroll
    for (int i = 0; i < 8; ++i) { v[i] = hr[tid + i * 256]; m = fmaxf(m, v[i]); }

    __shared__ float redm[4], reds[4];
    int wid = tid >> 6, lane = tid & 63;
    #pragma unroll
    for (int off = 32; off; off >>= 1) m = fmaxf(m, __shfl_down(m, off));
    if (lane == 0) redm[wid] = m;
    __syncthreads();
    m = fmaxf(fmaxf(redm[0], redm[1]), fmaxf(redm[2], redm[3]));

    float e[8];
    float s = 0.0f;
    #pragma unroll
    for (int i = 0; i < 8; ++i) { e[i] = expf(v[i] - m); s += e[i]; }
    #pragma unroll
    for (int off = 32; off; off >>= 1) s += __shfl_down(s, off);
    if (lane == 0) reds[wid] = s;
    __syncthreads();
    s = reds[0] + reds[1] + reds[2] + reds[3];

    float* o = out + ((size_t)b * MAXLEN + t) * VOCAB;
    #pragma unroll
    for (int i = 0; i < 8; ++i) o[tid + i * 256] = e[i] / s;
}

extern "C" void kernel_launch(void* const* d_in, const int* in_sizes, int n_in,
                              void* d_out, int out_size, void* d_ws, size_t ws_size,
                              hipStream_t stream) {
    const float* ip = (const float*)d_in[0];   // (16,16)
    const float* E  = (const float*)d_in[1];   // (2048,256)
    const float* Wk = (const float*)d_in[2];   // (256,8192)
    const float* Wr = (const float*)d_in[3];   // (2048,8192)
    const float* bv = (const float*)d_in[4];   // (8192,)

    char* w = (char*)d_ws;
    float* xz  = (float*)w;  w += (size_t)8 * 4 * NBATCH * 2048 * 4;   // 4 MB
    float* h   = (float*)w;  w += (size_t)32768 * 4;
    float* c   = (float*)w;  w += (size_t)32768 * 4;
    float* H   = (float*)w;  w += (size_t)262144 * 4;                  // 1 MB
    u16* XA  = (u16*)w;      w += (size_t)32768 * 2;                   // 64 KB
    u16* hA0 = (u16*)w;      w += (size_t)32768 * 2;
    u16* hA1 = (u16*)w;      w += (size_t)32768 * 2;
    u16* BWk = (u16*)w;      w += (size_t)2097152 * 2;                 // 4 MB
    u16* BW  = (u16*)w;      w += (size_t)16777216 * 2;                // 32 MB

    k_pack<<<9232, 256, 0, stream>>>(Wr, Wk, ip, E, BW, BWk, XA);
    k_xzmm0<<<128, 1024, 0, stream>>>(BWk, XA, bv, ip, xz, h, c, hA1, H);
    u16* hAbuf[2] = {hA0, hA1};
    for (int t = 1; t < MAXLEN; ++t)
        k_step<<<128, 1024, 0, stream>>>(BW, hAbuf[t & 1], hAbuf[(t + 1) & 1],
                                         xz, ip, h, c, H, t);
    k_softmax<<<128, 256, 0, stream>>>(H, (float*)d_out);
}